// Round 4
// baseline (845.914 us; speedup 1.0000x reference)
//
#include <hip/hip_runtime.h>
#include <math.h>

// Problem constants
#define N_B 32
#define L_S 4096
#define D_M 768
#define H_N 12
#define NCH 16          // l-chunks (256 rows each)
#define XP  776         // padded LDS row pitch (768+8): 2-way max bank alias

// ws layout (float offsets). NO zero-init required: every buffer is fully
// written before it is read (all split-k via plain partials, no atomics).
#define WS_QHP    0         // [16][768] qh split-k partials
#define WS_QK     12288     // [12][768] h-major
#define WS_QB     21504     // [12] (pad 64)
#define WS_MLC    21568     // [32*12][16] per-(n,h,lc) running max
#define WS_SLC    27712     // [32*12][16] per-(n,h,lc) running sum
#define WS_XBP    33856     // [16 lc][32 n][12 h][768 d] unnormalized partials
#define WS_OP     4752448   // [8 kk][32][768] o partials
#define WS_XAP    4949056   // [8 kk][32][768] xa partials
#define WS_XAS    5145664   // [32][768] summed xa (written by ln)
#define WS_Y      5170240   // [32][768]
#define WS_H1P    5194816   // [4 kk][32][3072] mlp1 partials
#define WS_MACCP  5588032   // [16 kk][32][768] mlp2 partials

// ---------------------------------------------------------------------------
// qh partials: qhp[ky][i] = 0.125*(probe[d0:d0+48] @ wq)[i] (+0.125*bq at ky0).
__global__ __launch_bounds__(256) void qh_kernel(
    const float* __restrict__ probe, const float* __restrict__ wq,
    const float* __restrict__ bq, float* __restrict__ qhp) {
    int i = blockIdx.x * 256 + threadIdx.x;
    int ky = blockIdx.y, d0 = ky * 48;
    float acc = 0.f;
    for (int dd = 0; dd < 48; ++dd)
        acc += probe[d0 + dd] * wq[(size_t)(d0 + dd) * 768 + i];
    acc *= 0.125f;
    if (ky == 0) acc += 0.125f * bq[i];
    qhp[ky * 768 + i] = acc;
}

// qk[h][d] = sum_e qh[h*64+e]*wk[d*768+h*64+e]; qb[h] = qh_h . bk_h.
// qh reconstructed from the 16 partials during staging (no atomics upstream).
__global__ __launch_bounds__(256) void qk_kernel(
    const float* __restrict__ qhp, const float* __restrict__ wk,
    const float* __restrict__ bk, float* __restrict__ qk,
    float* __restrict__ qb) {
    int h = blockIdx.x, dt = blockIdx.y, t = threadIdx.x;
    __shared__ float qh_s[64];
    if (t < 64) {
        float s = 0.f;
        #pragma unroll
        for (int k = 0; k < 16; ++k) s += qhp[k * 768 + h * 64 + t];
        qh_s[t] = s;
    }
    __syncthreads();
    int d = dt * 256 + t;
    const float4* wk4 = (const float4*)(wk + (size_t)d * 768 + h * 64);
    const float4* qh4 = (const float4*)qh_s;
    float acc = 0.f;
    #pragma unroll
    for (int e4 = 0; e4 < 16; ++e4) {
        float4 w = wk4[e4], q = qh4[e4];
        acc += w.x * q.x + w.y * q.y + w.z * q.z + w.w * q.w;
    }
    qk[h * 768 + d] = acc;
    if (dt == 0 && t < 64) {
        float v = qh_s[t] * bk[h * 64 + t];
        #pragma unroll
        for (int off = 32; off > 0; off >>= 1) v += __shfl_xor(v, off);
        if (t == 0) qb[h] = v;
    }
}

// ---------------------------------------------------------------------------
// Fused flash-style attention inner phase. Block = (lc, n): 256 rows of x,
// streamed ONCE through a double-buffered 4-row LDS tile (pitch 776).
// LDS-traffic-optimized layout:
//   phase1: thread t<192 = (h,q,r) with t = h*16+q*4+r. Within a wave each
//     x address is shared by 4 lanes (h's) and each qk address by 4 lanes
//     (r's) -> 4-way LDS broadcast, ~4x less LDS bank traffic than distinct.
//     2-shuffle (xor 4,8) quarter combine -> lg_s[r][h].
//   bookkeeping (t<12): online max/sum per head, tile weights w_s, rescale sc_s.
//   phase2: t<192 owns 4 contiguous cols: per l, 1 x b128 + 3 broadcast w b128.
// Output: xbp[lc][n][h][768] partials + per-chunk (m, s); exact merge via
// softmax linearity happens in oproj.
__global__ __launch_bounds__(256) void attn_fused(
    const float* __restrict__ x, const float* __restrict__ qk,
    const float* __restrict__ qb, float* __restrict__ xbp,
    float* __restrict__ mlc, float* __restrict__ slc) {
    __shared__ __align__(16) float qk_s[12 * XP];   // 37.2 KB
    __shared__ __align__(16) float xs[2 * 4 * XP];  // 24.8 KB
    __shared__ float lg_s[64], w_s[64], qb_s[16], ms_s[16], ss_s[16], sc_s[16];
    int lc = blockIdx.x, n = blockIdx.y, t = threadIdx.x;
    int lane = t & 63, w = t >> 6;
    size_t xbase = ((size_t)n * 4096 + lc * 256) * 768;

    // stage qk into padded rows; init state
    for (int i = t; i < 12 * 192; i += 256) {
        int hh = i / 192, c = i % 192;
        *(float4*)&qk_s[hh * XP + c * 4] = ((const float4*)qk)[i];
    }
    if (t < 12) { qb_s[t] = qb[t]; ms_s[t] = -1e30f; ss_s[t] = 0.f; }
    // stage subtile 0 into buffer 0
    {
        const float4* s0 = (const float4*)(x + xbase);
        for (int j = t; j < 768; j += 256)
            *(float4*)&xs[(j / 192) * XP + (j % 192) * 4] = s0[j];
    }
    float4 acc4[12];
    #pragma unroll
    for (int h = 0; h < 12; ++h) acc4[h] = make_float4(0.f, 0.f, 0.f, 0.f);
    int r1 = t & 3, q1 = (t >> 2) & 3, h1 = t >> 4;   // valid for t<192
    __syncthreads();

    int p = 0;
    for (int it = 0; it < 64; ++it) {
        // wave 3: stage subtile it+1 into buffer p^1 (latency hides under
        // waves 0-2's phase1+phase2; visibility fenced by the end barrier)
        if (w == 3 && it + 1 < 64) {
            const float4* src = (const float4*)(x + xbase + (size_t)(it + 1) * 3072);
            #pragma unroll
            for (int j = 0; j < 12; ++j) {
                int f = lane + 64 * j;
                float4 v = src[f];
                *(float4*)&xs[(p ^ 1) * 4 * XP + (f / 192) * XP + (f % 192) * 4] = v;
            }
        }
        // phase1: 48 dots (4r x 12h), 4-way-broadcast LDS reads
        if (t < 192) {
            const float4* xr = (const float4*)&xs[p * 4 * XP + r1 * XP];
            const float4* kr = (const float4*)&qk_s[h1 * XP];
            float a = 0.f;
            #pragma unroll 8
            for (int s = 0; s < 48; ++s) {
                int idx = s * 4 + q1;
                float4 xv = xr[idx], kv = kr[idx];
                a += xv.x * kv.x + xv.y * kv.y + xv.z * kv.z + xv.w * kv.w;
            }
            a += __shfl_xor(a, 4);
            a += __shfl_xor(a, 8);
            if (q1 == 0) lg_s[r1 * 16 + h1] = a + qb_s[h1];
        }
        __syncthreads();
        // bookkeeping: thread h<12, online softmax state update
        if (t < 12) {
            float l0 = lg_s[0 * 16 + t], l1 = lg_s[1 * 16 + t];
            float l2 = lg_s[2 * 16 + t], l3 = lg_s[3 * 16 + t];
            float mt = fmaxf(fmaxf(l0, l1), fmaxf(l2, l3));
            float mo = ms_s[t];
            float mn = fmaxf(mo, mt);
            float sc = __expf(mo - mn);
            float e0 = __expf(l0 - mn), e1 = __expf(l1 - mn);
            float e2 = __expf(l2 - mn), e3 = __expf(l3 - mn);
            w_s[0 * 16 + t] = e0; w_s[1 * 16 + t] = e1;
            w_s[2 * 16 + t] = e2; w_s[3 * 16 + t] = e3;
            ms_s[t] = mn;
            ss_s[t] = ss_s[t] * sc + (e0 + e1 + e2 + e3);
            sc_s[t] = sc;
        }
        __syncthreads();
        // phase2: t<192 owns 4 contiguous d-cols; vector LDS reads only
        if (t < 192) {
            const float* xb = &xs[p * 4 * XP];
            const float4* w4 = (const float4*)w_s;
            const float4* sc4 = (const float4*)sc_s;
            float4 sa = sc4[0], sb = sc4[1], sc = sc4[2];
            acc4[0].x *= sa.x; acc4[0].y *= sa.x; acc4[0].z *= sa.x; acc4[0].w *= sa.x;
            acc4[1].x *= sa.y; acc4[1].y *= sa.y; acc4[1].z *= sa.y; acc4[1].w *= sa.y;
            acc4[2].x *= sa.z; acc4[2].y *= sa.z; acc4[2].z *= sa.z; acc4[2].w *= sa.z;
            acc4[3].x *= sa.w; acc4[3].y *= sa.w; acc4[3].z *= sa.w; acc4[3].w *= sa.w;
            acc4[4].x *= sb.x; acc4[4].y *= sb.x; acc4[4].z *= sb.x; acc4[4].w *= sb.x;
            acc4[5].x *= sb.y; acc4[5].y *= sb.y; acc4[5].z *= sb.y; acc4[5].w *= sb.y;
            acc4[6].x *= sb.z; acc4[6].y *= sb.z; acc4[6].z *= sb.z; acc4[6].w *= sb.z;
            acc4[7].x *= sb.w; acc4[7].y *= sb.w; acc4[7].z *= sb.w; acc4[7].w *= sb.w;
            acc4[8].x *= sc.x; acc4[8].y *= sc.x; acc4[8].z *= sc.x; acc4[8].w *= sc.x;
            acc4[9].x *= sc.y; acc4[9].y *= sc.y; acc4[9].z *= sc.y; acc4[9].w *= sc.y;
            acc4[10].x *= sc.z; acc4[10].y *= sc.z; acc4[10].z *= sc.z; acc4[10].w *= sc.z;
            acc4[11].x *= sc.w; acc4[11].y *= sc.w; acc4[11].z *= sc.w; acc4[11].w *= sc.w;
            #pragma unroll
            for (int l = 0; l < 4; ++l) {
                float4 xv = *(const float4*)&xb[l * XP + 4 * t];
                float4 wa = w4[l * 4], wb = w4[l * 4 + 1], wc = w4[l * 4 + 2];
                acc4[0].x += wa.x * xv.x; acc4[0].y += wa.x * xv.y; acc4[0].z += wa.x * xv.z; acc4[0].w += wa.x * xv.w;
                acc4[1].x += wa.y * xv.x; acc4[1].y += wa.y * xv.y; acc4[1].z += wa.y * xv.z; acc4[1].w += wa.y * xv.w;
                acc4[2].x += wa.z * xv.x; acc4[2].y += wa.z * xv.y; acc4[2].z += wa.z * xv.z; acc4[2].w += wa.z * xv.w;
                acc4[3].x += wa.w * xv.x; acc4[3].y += wa.w * xv.y; acc4[3].z += wa.w * xv.z; acc4[3].w += wa.w * xv.w;
                acc4[4].x += wb.x * xv.x; acc4[4].y += wb.x * xv.y; acc4[4].z += wb.x * xv.z; acc4[4].w += wb.x * xv.w;
                acc4[5].x += wb.y * xv.x; acc4[5].y += wb.y * xv.y; acc4[5].z += wb.y * xv.z; acc4[5].w += wb.y * xv.w;
                acc4[6].x += wb.z * xv.x; acc4[6].y += wb.z * xv.y; acc4[6].z += wb.z * xv.z; acc4[6].w += wb.z * xv.w;
                acc4[7].x += wb.w * xv.x; acc4[7].y += wb.w * xv.y; acc4[7].z += wb.w * xv.z; acc4[7].w += wb.w * xv.w;
                acc4[8].x += wc.x * xv.x; acc4[8].y += wc.x * xv.y; acc4[8].z += wc.x * xv.z; acc4[8].w += wc.x * xv.w;
                acc4[9].x += wc.y * xv.x; acc4[9].y += wc.y * xv.y; acc4[9].z += wc.y * xv.z; acc4[9].w += wc.y * xv.w;
                acc4[10].x += wc.z * xv.x; acc4[10].y += wc.z * xv.y; acc4[10].z += wc.z * xv.z; acc4[10].w += wc.z * xv.w;
                acc4[11].x += wc.w * xv.x; acc4[11].y += wc.w * xv.y; acc4[11].z += wc.w * xv.z; acc4[11].w += wc.w * xv.w;
            }
        }
        __syncthreads();   // all reads of buf p done; stage (it+1) visible
        p ^= 1;
    }
    // write partials + per-chunk stats
    size_t ob = ((size_t)(lc * 32 + n)) * 12 * 768;
    if (t < 192) {
        #pragma unroll
        for (int h = 0; h < 12; ++h)
            *(float4*)&xbp[ob + h * 768 + 4 * t] = acc4[h];
    }
    if (t < 12) {
        mlc[(n * 12 + t) * 16 + lc] = ms_s[t];
        slc[(n * 12 + t) * 16 + lc] = ss_s[t];
    }
}

// ---------------------------------------------------------------------------
// o partials: op[kk][n][h*64+e] = sum_{d in kk} xbar[n,h,d]*wv[d,h,e] (+bv@kk0).
// Grid (12 h, 8 kk). Softmax merge (was merge_kernel) computed in-block from
// (mlc,slc); xbar reconstructed by scale-summing the 16 chunk partials.
__global__ __launch_bounds__(256) void oproj_kernel(
    const float* __restrict__ xbp, const float* __restrict__ mlc,
    const float* __restrict__ slc, const float* __restrict__ wv,
    const float* __restrict__ bv, float* __restrict__ op) {
    int h = blockIdx.x, kk = blockIdx.y, t = threadIdx.x;
    int d0 = kk * 96;
    __shared__ __align__(16) float wv_s[96 * 64];
    __shared__ __align__(16) float xb_s[96 * 32];
    __shared__ float scl_s[16 * 32];   // [lc][nn]
    if (t < 32) {
        float M = -1e30f;
        #pragma unroll
        for (int c = 0; c < 16; ++c) M = fmaxf(M, mlc[(t * 12 + h) * 16 + c]);
        float e[16], T = 0.f;
        #pragma unroll
        for (int c = 0; c < 16; ++c) {
            e[c] = __expf(mlc[(t * 12 + h) * 16 + c] - M);
            T += slc[(t * 12 + h) * 16 + c] * e[c];
        }
        float inv = 1.f / T;
        #pragma unroll
        for (int c = 0; c < 16; ++c) scl_s[c * 32 + t] = e[c] * inv;
    }
    for (int i = t; i < 96 * 64; i += 256) {
        int d = i >> 6, e = i & 63;
        wv_s[i] = wv[(size_t)(d0 + d) * 768 + h * 64 + e];
    }
    __syncthreads();
    for (int i = t; i < 96 * 32; i += 256) {
        int d = i >> 5, nn = i & 31;
        float s = 0.f;
        #pragma unroll
        for (int lcc = 0; lcc < 16; ++lcc)
            s += xbp[(((size_t)lcc * 32 + nn) * 12 + h) * 768 + d0 + d]
               * scl_s[lcc * 32 + nn];
        xb_s[i] = s;
    }
    __syncthreads();
    int e = t & 63, ng = t >> 6;
    float acc[8] = {0, 0, 0, 0, 0, 0, 0, 0};
    for (int d = 0; d < 96; ++d) {
        float wvv = wv_s[d * 64 + e];
        const float4* xb4 = (const float4*)&xb_s[d * 32 + ng * 8];
        float4 p0 = xb4[0], p1 = xb4[1];
        acc[0] += p0.x * wvv; acc[1] += p0.y * wvv; acc[2] += p0.z * wvv; acc[3] += p0.w * wvv;
        acc[4] += p1.x * wvv; acc[5] += p1.y * wvv; acc[6] += p1.z * wvv; acc[7] += p1.w * wvv;
    }
    float bvv = (kk == 0) ? bv[h * 64 + e] : 0.f;
    #pragma unroll
    for (int k = 0; k < 8; ++k)
        op[(size_t)kk * 24576 + (size_t)(ng * 8 + k) * 768 + h * 64 + e] = acc[k] + bvv;
}

// xa partials: xap[kk][n][d] = sum_{i in kk} o[n][i]*wo[i*768+d] (+bo@kk0).
// Grid (3 dtile, 8 kk). o summed from its 8 partials during staging.
__global__ __launch_bounds__(256) void xaproj_kernel(
    const float* __restrict__ op, const float* __restrict__ wo,
    const float* __restrict__ bo, float* __restrict__ xap) {
    int dt = blockIdx.x, kk = blockIdx.y, t = threadIdx.x;
    int i0 = kk * 96;
    __shared__ __align__(16) float o_s[96 * 32];
    for (int idx = t; idx < 96 * 32; idx += 256) {
        int i = idx >> 5, nn = idx & 31;
        float s = 0.f;
        #pragma unroll
        for (int pp = 0; pp < 8; ++pp)
            s += op[(size_t)pp * 24576 + (size_t)nn * 768 + i0 + i];
        o_s[idx] = s;
    }
    __syncthreads();
    int d = dt * 256 + t;
    float acc[32];
    #pragma unroll
    for (int nn = 0; nn < 32; ++nn) acc[nn] = 0.f;
    for (int i = 0; i < 96; ++i) {
        float w = wo[(size_t)(i0 + i) * 768 + d];
        const float4* o4 = (const float4*)&o_s[i * 32];
        #pragma unroll
        for (int qq = 0; qq < 8; ++qq) {
            float4 f = o4[qq];
            acc[qq * 4 + 0] += f.x * w; acc[qq * 4 + 1] += f.y * w;
            acc[qq * 4 + 2] += f.z * w; acc[qq * 4 + 3] += f.w * w;
        }
    }
    float bov = (kk == 0) ? bo[d] : 0.f;
    #pragma unroll
    for (int nn = 0; nn < 32; ++nn)
        xap[(size_t)kk * 24576 + (size_t)nn * 768 + d] = acc[nn] + bov;
}

// ---------------------------------------------------------------------------
// xa = sum of 8 partials (stored to xas for the residual); y = LayerNorm(xa).
__global__ __launch_bounds__(256) void ln_kernel(
    const float* __restrict__ xap, const float* __restrict__ ln_scale,
    const float* __restrict__ ln_bias, float* __restrict__ xas,
    float* __restrict__ y) {
    int n = blockIdx.x, tid = threadIdx.x;
    __shared__ float xs[768];
    __shared__ float red[4];
    for (int i = tid; i < 768; i += 256) {
        float s = 0.f;
        #pragma unroll
        for (int pp = 0; pp < 8; ++pp)
            s += xap[(size_t)pp * 24576 + (size_t)n * 768 + i];
        xs[i] = s;
        xas[(size_t)n * 768 + i] = s;
    }
    __syncthreads();
    float lsum = 0.f;
    for (int i = tid; i < 768; i += 256) lsum += xs[i];
    #pragma unroll
    for (int off = 32; off > 0; off >>= 1) lsum += __shfl_xor(lsum, off);
    int wave = tid >> 6;
    if ((tid & 63) == 0) red[wave] = lsum;
    __syncthreads();
    float mu = (red[0] + red[1] + red[2] + red[3]) * (1.f / 768.f);
    __syncthreads();
    float lsq = 0.f;
    for (int i = tid; i < 768; i += 256) { float c = xs[i] - mu; lsq += c * c; }
    #pragma unroll
    for (int off = 32; off > 0; off >>= 1) lsq += __shfl_xor(lsq, off);
    if ((tid & 63) == 0) red[wave] = lsq;
    __syncthreads();
    float var = (red[0] + red[1] + red[2] + red[3]) * (1.f / 768.f);
    float rs = rsqrtf(var + 1e-6f);
    for (int i = tid; i < 768; i += 256)
        y[(size_t)n * 768 + i] = (xs[i] - mu) * rs * ln_scale[i] + ln_bias[i];
}

// ---------------------------------------------------------------------------
// h1 partials: h1p[kk][n][j] = sum_{d in kk(192)} y[n][d]*w1[d][j]. Grid (12,4).
__global__ __launch_bounds__(256) void mlp1_kernel(
    const float* __restrict__ y, const float* __restrict__ w1,
    float* __restrict__ h1p) {
    int jt = blockIdx.x, kk = blockIdx.y, t = threadIdx.x;
    int d0 = kk * 192;
    __shared__ __align__(16) float y_s[192 * 32];
    for (int idx = t; idx < 192 * 32; idx += 256) {
        int d = idx >> 5, nn = idx & 31;
        y_s[idx] = y[(size_t)nn * 768 + d0 + d];
    }
    __syncthreads();
    int j = jt * 256 + t;
    float acc[32];
    #pragma unroll
    for (int nn = 0; nn < 32; ++nn) acc[nn] = 0.f;
    for (int d = 0; d < 192; ++d) {
        float w = w1[(size_t)(d0 + d) * 3072 + j];
        const float4* y4 = (const float4*)&y_s[d * 32];
        #pragma unroll
        for (int qq = 0; qq < 8; ++qq) {
            float4 f = y4[qq];
            acc[qq * 4 + 0] += f.x * w; acc[qq * 4 + 1] += f.y * w;
            acc[qq * 4 + 2] += f.z * w; acc[qq * 4 + 3] += f.w * w;
        }
    }
    #pragma unroll
    for (int nn = 0; nn < 32; ++nn)
        h1p[(size_t)kk * 98304 + (size_t)nn * 3072 + j] = acc[nn];
}

// macc partials: maccp[kk][n][d] = sum_{j in kk(192)} gelu(h1+b1)[n][j]*w2[j][d].
// Grid (3 dtile, 16 kk). h1 summed from its 4 partials + gelu during staging.
__global__ __launch_bounds__(256) void mlp2_kernel(
    const float* __restrict__ h1p, const float* __restrict__ b1,
    const float* __restrict__ w2, float* __restrict__ maccp) {
    int dt = blockIdx.x, kk = blockIdx.y, t = threadIdx.x;
    int j0 = kk * 192;
    __shared__ __align__(16) float h_s[192 * 32];
    for (int idx = t; idx < 192 * 32; idx += 256) {
        int j = idx >> 5, nn = idx & 31;
        float tv = b1[j0 + j];
        #pragma unroll
        for (int pp = 0; pp < 4; ++pp)
            tv += h1p[(size_t)pp * 98304 + (size_t)nn * 3072 + j0 + j];
        float u = 0.7978845608028654f * (tv + 0.044715f * tv * tv * tv);
        h_s[idx] = 0.5f * tv * (1.f + tanhf(u));
    }
    __syncthreads();
    int d = dt * 256 + t;
    float acc[32];
    #pragma unroll
    for (int nn = 0; nn < 32; ++nn) acc[nn] = 0.f;
    for (int j = 0; j < 192; ++j) {
        float w = w2[(size_t)(j0 + j) * 768 + d];
        const float4* h4 = (const float4*)&h_s[j * 32];
        #pragma unroll
        for (int qq = 0; qq < 8; ++qq) {
            float4 f = h4[qq];
            acc[qq * 4 + 0] += f.x * w; acc[qq * 4 + 1] += f.y * w;
            acc[qq * 4 + 2] += f.z * w; acc[qq * 4 + 3] += f.w * w;
        }
    }
    #pragma unroll
    for (int nn = 0; nn < 32; ++nn)
        maccp[(size_t)kk * 24576 + (size_t)nn * 768 + d] = acc[nn];
}

// out = xas + b2 + sum_16 maccp. Grid 32 n.
__global__ __launch_bounds__(256) void final_kernel(
    const float* __restrict__ xas, const float* __restrict__ b2,
    const float* __restrict__ maccp, float* __restrict__ out) {
    int n = blockIdx.x, t = threadIdx.x;
    for (int i = t; i < 768; i += 256) {
        float s = xas[(size_t)n * 768 + i] + b2[i];
        #pragma unroll
        for (int k = 0; k < 16; ++k)
            s += maccp[(size_t)k * 24576 + (size_t)n * 768 + i];
        out[(size_t)n * 768 + i] = s;
    }
}

// ---------------------------------------------------------------------------
extern "C" void kernel_launch(void* const* d_in, const int* in_sizes, int n_in,
                              void* d_out, int out_size, void* d_ws, size_t ws_size,
                              hipStream_t stream) {
    const float* x        = (const float*)d_in[0];
    const float* probe    = (const float*)d_in[1];
    const float* wq       = (const float*)d_in[2];
    const float* bq       = (const float*)d_in[3];
    const float* wk       = (const float*)d_in[4];
    const float* bk       = (const float*)d_in[5];
    const float* wv       = (const float*)d_in[6];
    const float* bv       = (const float*)d_in[7];
    const float* wo       = (const float*)d_in[8];
    const float* bo       = (const float*)d_in[9];
    const float* ln_scale = (const float*)d_in[10];
    const float* ln_bias  = (const float*)d_in[11];
    const float* w1       = (const float*)d_in[12];
    const float* b1       = (const float*)d_in[13];
    const float* w2       = (const float*)d_in[14];
    const float* b2       = (const float*)d_in[15];
    float* out = (float*)d_out;
    float* ws  = (float*)d_ws;

    float* qhp   = ws + WS_QHP;
    float* qk    = ws + WS_QK;
    float* qb    = ws + WS_QB;
    float* mlc   = ws + WS_MLC;
    float* slc   = ws + WS_SLC;
    float* xbp   = ws + WS_XBP;
    float* op    = ws + WS_OP;
    float* xap   = ws + WS_XAP;
    float* xas   = ws + WS_XAS;
    float* y     = ws + WS_Y;
    float* h1p   = ws + WS_H1P;
    float* maccp = ws + WS_MACCP;

    qh_kernel<<<dim3(3, 16), 256, 0, stream>>>(probe, wq, bq, qhp);
    qk_kernel<<<dim3(12, 3), 256, 0, stream>>>(qhp, wk, bk, qk, qb);
    attn_fused<<<dim3(NCH, 32), 256, 0, stream>>>(x, qk, qb, xbp, mlc, slc);
    oproj_kernel<<<dim3(12, 8), 256, 0, stream>>>(xbp, mlc, slc, wv, bv, op);
    xaproj_kernel<<<dim3(3, 8), 256, 0, stream>>>(op, wo, bo, xap);
    ln_kernel<<<N_B, 256, 0, stream>>>(xap, ln_scale, ln_bias, xas, y);
    mlp1_kernel<<<dim3(12, 4), 256, 0, stream>>>(y, w1, h1p);
    mlp2_kernel<<<dim3(3, 16), 256, 0, stream>>>(h1p, b1, w2, maccp);
    final_kernel<<<N_B, 256, 0, stream>>>(xas, b2, maccp, out);
}